// Round 1
// baseline (2933.288 us; speedup 1.0000x reference)
//
#include <hip/hip_runtime.h>

#define N_NODES 50000
#define N_EDGES 800000
#define DIM 128

// ---------------- degree / norm ----------------

__global__ __launch_bounds__(256) void deg_kernel(const int* __restrict__ dst,
                                                  float* __restrict__ deg, int nE) {
    int e = blockIdx.x * 256 + threadIdx.x;
    if (e < nE) atomicAdd(&deg[dst[e]], 1.0f);
}

__global__ __launch_bounds__(256) void dinv_kernel(float* __restrict__ deg, int n) {
    int i = blockIdx.x * 256 + threadIdx.x;
    if (i < n) deg[i] = rsqrtf(deg[i] + 1.0f);   // +1 self-loop; in-place deg -> dinv
}

// ---------------- GEMM: O[n,128] = X[n,128] @ W[128,128] ----------------
// 16 rows per block, X rows staged in LDS, W streamed through L1/L2
// (W is 64 KB, fully L2-resident; each wave reads coalesced 256B rows).

__global__ __launch_bounds__(256) void gemm_xw(const float* __restrict__ X,
                                               const float* __restrict__ W,
                                               float* __restrict__ O, int nrows) {
    __shared__ float Xs[16][128];
    const int rbase = blockIdx.x * 16;
    const int t = threadIdx.x;

    for (int i = t; i < 16 * 128; i += 256) {
        int r = i >> 7, c = i & 127;
        int gr = rbase + r;
        Xs[r][c] = (gr < nrows) ? X[(size_t)gr * DIM + c] : 0.0f;
    }
    __syncthreads();

    const int c  = t & 127;
    const int rg = (t >> 7) * 8;   // thread group 0 -> rows 0..7, group 1 -> rows 8..15
    float acc[8] = {0, 0, 0, 0, 0, 0, 0, 0};

    for (int k = 0; k < 128; ++k) {
        float w = W[k * DIM + c];
#pragma unroll
        for (int j = 0; j < 8; ++j) acc[j] += Xs[rg + j][k] * w;
    }

#pragma unroll
    for (int j = 0; j < 8; ++j) {
        int r = rbase + rg + j;
        if (r < nrows) O[(size_t)r * DIM + c] = acc[j];
    }
}

// ---------------- edge scatter: out[dst] += h[src] * norm ----------------
// one thread per (edge, 4-channel group): float4 gather, 4 float atomics.

__global__ __launch_bounds__(256) void scatter_kernel(const float4* __restrict__ H,
                                                      const int* __restrict__ src,
                                                      const int* __restrict__ dst,
                                                      const float* __restrict__ dinv,
                                                      float* __restrict__ out) {
    int idx = blockIdx.x * 256 + threadIdx.x;       // e*32 + q,  max 25.6M fits int
    if (idx >= N_EDGES * 32) return;
    int e = idx >> 5, q = idx & 31;
    int s = src[e], d = dst[e];
    float nrm = dinv[s] * dinv[d];
    float4 v = H[(size_t)s * 32 + q];
    float* o = out + (size_t)d * 128 + q * 4;
    atomicAdd(o + 0, v.x * nrm);
    atomicAdd(o + 1, v.y * nrm);
    atomicAdd(o + 2, v.z * nrm);
    atomicAdd(o + 3, v.w * nrm);
}

// ---------------- epilogues ----------------
// layer1: agg <- relu(agg + h*dinv^2 + b)   (self-loop term folded in; in place)

__global__ __launch_bounds__(256) void finalize_relu(float* __restrict__ agg,
                                                     const float* __restrict__ H,
                                                     const float* __restrict__ dinv,
                                                     const float* __restrict__ b) {
    int idx = blockIdx.x * 256 + threadIdx.x;
    if (idx >= N_NODES * DIM) return;
    int i = idx >> 7, c = idx & 127;
    float di = dinv[i];
    float v = agg[idx] + H[idx] * di * di + b[c];
    agg[idx] = fmaxf(v, 0.0f);
}

// layer2: out <- agg + h*dinv^2 + b

__global__ __launch_bounds__(256) void finalize_out(const float* __restrict__ agg,
                                                    const float* __restrict__ H,
                                                    const float* __restrict__ dinv,
                                                    const float* __restrict__ b,
                                                    float* __restrict__ out) {
    int idx = blockIdx.x * 256 + threadIdx.x;
    if (idx >= N_NODES * DIM) return;
    int i = idx >> 7, c = idx & 127;
    float di = dinv[i];
    out[idx] = agg[idx] + H[idx] * di * di + b[c];
}

// ---------------- launch ----------------

extern "C" void kernel_launch(void* const* d_in, const int* in_sizes, int n_in,
                              void* d_out, int out_size, void* d_ws, size_t ws_size,
                              hipStream_t stream) {
    const float* x  = (const float*)d_in[0];
    const int*   ei = (const int*)d_in[1];
    const float* W1 = (const float*)d_in[2];
    const float* b1 = (const float*)d_in[3];
    const float* W2 = (const float*)d_in[4];
    const float* b2 = (const float*)d_in[5];
    float* out = (float*)d_out;

    const int* src = ei;             // edge_index[0]
    const int* dst = ei + N_EDGES;   // edge_index[1]

    float* deg  = (float*)d_ws;                         // N_NODES (becomes dinv)
    float* bufA = deg + ((N_NODES + 255) & ~255);       // N_NODES*DIM
    float* bufB = bufA + (size_t)N_NODES * DIM;         // N_NODES*DIM

    const size_t featBytes = (size_t)N_NODES * DIM * sizeof(float);
    const int gemmBlocks  = (N_NODES + 15) / 16;                 // 3125
    const int scatBlocks  = (N_EDGES * 32 + 255) / 256;          // 100000
    const int elemBlocks  = (N_NODES * DIM + 255) / 256;         // 25000

    // degrees -> dinv
    hipMemsetAsync(deg, 0, N_NODES * sizeof(float), stream);
    deg_kernel<<<(N_EDGES + 255) / 256, 256, 0, stream>>>(dst, deg, N_EDGES);
    dinv_kernel<<<(N_NODES + 255) / 256, 256, 0, stream>>>(deg, N_NODES);

    // layer 1: h1 = x@W1 -> bufA ; agg -> bufB ; relu epilogue in place (bufB)
    gemm_xw<<<gemmBlocks, 256, 0, stream>>>(x, W1, bufA, N_NODES);
    hipMemsetAsync(bufB, 0, featBytes, stream);
    scatter_kernel<<<scatBlocks, 256, 0, stream>>>((const float4*)bufA, src, dst, deg, bufB);
    finalize_relu<<<elemBlocks, 256, 0, stream>>>(bufB, bufA, deg, b1);

    // layer 2: h2 = hrelu@W2 -> bufA ; agg -> bufB (free after gemm consumed it)
    gemm_xw<<<gemmBlocks, 256, 0, stream>>>(bufB, W2, bufA, N_NODES);
    hipMemsetAsync(bufB, 0, featBytes, stream);
    scatter_kernel<<<scatBlocks, 256, 0, stream>>>((const float4*)bufA, src, dst, deg, bufB);
    finalize_out<<<elemBlocks, 256, 0, stream>>>(bufB, bufA, deg, b2, out);
}

// Round 2
// 402.932 us; speedup vs baseline: 7.2799x; 7.2799x over previous
//
#include <hip/hip_runtime.h>

#define N_NODES 50000
#define N_EDGES 800000
#define DIM 128

// ---------------- degree histogram (int) ----------------

__global__ __launch_bounds__(256) void deg_kernel(const int* __restrict__ dst,
                                                  int* __restrict__ degi, int nE) {
    int e = blockIdx.x * 256 + threadIdx.x;
    if (e < nE) atomicAdd(&degi[dst[e]], 1);
}

__global__ __launch_bounds__(256) void dinv_kernel(const int* __restrict__ degi,
                                                   float* __restrict__ dinv, int n) {
    int i = blockIdx.x * 256 + threadIdx.x;
    if (i < n) dinv[i] = rsqrtf((float)degi[i] + 1.0f);   // +1 self-loop
}

// ---------------- single-block exclusive scan: rowptr[0..n] ----------------

__global__ __launch_bounds__(1024) void scan_kernel(const int* __restrict__ cnt,
                                                    int* __restrict__ rowptr,
                                                    int* __restrict__ cursor, int n) {
    __shared__ int wsum[16];
    __shared__ int carry_s;
    const int t = threadIdx.x;
    const int lane = t & 63;
    const int wid = t >> 6;
    if (t == 0) { carry_s = 0; rowptr[0] = 0; }
    __syncthreads();
    for (int base = 0; base < n; base += 1024) {
        int i = base + t;
        int v = (i < n) ? cnt[i] : 0;
        int incl = v;
#pragma unroll
        for (int off = 1; off < 64; off <<= 1) {
            int u = __shfl_up(incl, off, 64);
            if (lane >= off) incl += u;
        }
        if (lane == 63) wsum[wid] = incl;
        __syncthreads();
        if (wid == 0) {
            int wv = (lane < 16) ? wsum[lane] : 0;
#pragma unroll
            for (int off = 1; off < 16; off <<= 1) {
                int u = __shfl_up(wv, off, 64);
                if (lane >= off) wv += u;
            }
            if (lane < 16) wsum[lane] = wv;
        }
        __syncthreads();
        int waveoff = (wid > 0) ? wsum[wid - 1] : 0;
        int inclTot = carry_s + waveoff + incl;
        if (i < n) { rowptr[i + 1] = inclTot; cursor[i] = inclTot - v; }
        __syncthreads();
        if (t == 1023) carry_s = inclTot;     // = old carry + chunk total
        __syncthreads();
    }
}

// ---------------- CSR fill (grouped by dst, entries = src) ----------------

__global__ __launch_bounds__(256) void fill_kernel(const int* __restrict__ src,
                                                   const int* __restrict__ dst,
                                                   int* __restrict__ cursor,
                                                   int* __restrict__ csr, int nE) {
    int e = blockIdx.x * 256 + threadIdx.x;
    if (e >= nE) return;
    int d = dst[e];
    int pos = atomicAdd(&cursor[d], 1);
    csr[pos] = src[e];
}

// ---------------- GEMM: O[n,128] = (X[n,128] @ W[128,128]) * dinv[row] -----

__global__ __launch_bounds__(256) void gemm_xw(const float* __restrict__ X,
                                               const float* __restrict__ W,
                                               const float* __restrict__ dinv,
                                               float* __restrict__ O, int nrows) {
    __shared__ float Xs[16][128];
    const int rbase = blockIdx.x * 16;
    const int t = threadIdx.x;

    for (int i = t; i < 16 * 128; i += 256) {
        int r = i >> 7, c = i & 127;
        int gr = rbase + r;
        Xs[r][c] = (gr < nrows) ? X[(size_t)gr * DIM + c] : 0.0f;
    }
    __syncthreads();

    const int c  = t & 127;
    const int rg = (t >> 7) * 8;
    float acc[8] = {0, 0, 0, 0, 0, 0, 0, 0};

    for (int k = 0; k < 128; ++k) {
        float w = W[k * DIM + c];
#pragma unroll
        for (int j = 0; j < 8; ++j) acc[j] += Xs[rg + j][k] * w;
    }

#pragma unroll
    for (int j = 0; j < 8; ++j) {
        int r = rbase + rg + j;
        if (r < nrows) O[(size_t)r * DIM + c] = acc[j] * dinv[r];
    }
}

// ---------------- CSR aggregate: out[d] = dinv[d]*(sum hp[s] + hp[d]) + b --
// one wave per node, float2 per lane (128 channels / 64 lanes)

__global__ __launch_bounds__(256) void aggregate_kernel(const float2* __restrict__ H2,
                                                        const int* __restrict__ rowptr,
                                                        const int* __restrict__ csr,
                                                        const float* __restrict__ dinv,
                                                        const float* __restrict__ b,
                                                        float2* __restrict__ out,
                                                        int relu) {
    int node = blockIdx.x * 4 + (threadIdx.x >> 6);
    if (node >= N_NODES) return;
    int lane = threadIdx.x & 63;

    float2 acc = H2[(size_t)node * 64 + lane];       // self-loop term hp[d]
    int beg = rowptr[node], end = rowptr[node + 1];
    int j = beg;
    // unroll-by-4 to keep 4 gathers in flight
    for (; j + 4 <= end; j += 4) {
        int s0 = csr[j], s1 = csr[j + 1], s2 = csr[j + 2], s3 = csr[j + 3];
        float2 v0 = H2[(size_t)s0 * 64 + lane];
        float2 v1 = H2[(size_t)s1 * 64 + lane];
        float2 v2 = H2[(size_t)s2 * 64 + lane];
        float2 v3 = H2[(size_t)s3 * 64 + lane];
        acc.x += v0.x + v1.x + v2.x + v3.x;
        acc.y += v0.y + v1.y + v2.y + v3.y;
    }
    for (; j < end; ++j) {
        int s = csr[j];
        float2 v = H2[(size_t)s * 64 + lane];
        acc.x += v.x; acc.y += v.y;
    }

    float di = dinv[node];
    int c = lane * 2;
    float o0 = acc.x * di + b[c];
    float o1 = acc.y * di + b[c + 1];
    if (relu) { o0 = fmaxf(o0, 0.0f); o1 = fmaxf(o1, 0.0f); }
    out[(size_t)node * 64 + lane] = make_float2(o0, o1);
}

// ---------------- launch ----------------

extern "C" void kernel_launch(void* const* d_in, const int* in_sizes, int n_in,
                              void* d_out, int out_size, void* d_ws, size_t ws_size,
                              hipStream_t stream) {
    const float* x  = (const float*)d_in[0];
    const int*   ei = (const int*)d_in[1];
    const float* W1 = (const float*)d_in[2];
    const float* b1 = (const float*)d_in[3];
    const float* W2 = (const float*)d_in[4];
    const float* b2 = (const float*)d_in[5];
    float* out = (float*)d_out;

    const int* src = ei;             // edge_index[0]
    const int* dst = ei + N_EDGES;   // edge_index[1]

    // workspace layout (all 1KB-aligned)
    char* p = (char*)d_ws;
    int*   degi   = (int*)p;                 p += ((N_NODES * 4 + 1023) & ~1023);
    float* dinv   = (float*)p;               p += ((N_NODES * 4 + 1023) & ~1023);
    int*   rowptr = (int*)p;                 p += (((N_NODES + 1) * 4 + 1023) & ~1023);
    int*   cursor = (int*)p;                 p += ((N_NODES * 4 + 1023) & ~1023);
    int*   csr    = (int*)p;                 p += ((N_EDGES * 4 + 1023) & ~1023);
    float* bufA   = (float*)p;               p += (size_t)N_NODES * DIM * sizeof(float);
    float* bufB   = (float*)p;

    const int gemmBlocks = (N_NODES + 15) / 16;       // 3125
    const int aggBlocks  = (N_NODES + 3) / 4;         // 12500
    const int nodeBlocks = (N_NODES + 255) / 256;
    const int edgeBlocks = (N_EDGES + 255) / 256;

    // ---- build CSR (grouped by dst) + dinv ----
    hipMemsetAsync(degi, 0, N_NODES * sizeof(int), stream);
    deg_kernel<<<edgeBlocks, 256, 0, stream>>>(dst, degi, N_EDGES);
    dinv_kernel<<<nodeBlocks, 256, 0, stream>>>(degi, dinv, N_NODES);
    scan_kernel<<<1, 1024, 0, stream>>>(degi, rowptr, cursor, N_NODES);
    fill_kernel<<<edgeBlocks, 256, 0, stream>>>(src, dst, cursor, csr, N_EDGES);

    // ---- layer 1: hp1 = (x@W1)*dinv -> bufA ; aggregate+bias+relu -> bufB ----
    gemm_xw<<<gemmBlocks, 256, 0, stream>>>(x, W1, dinv, bufA, N_NODES);
    aggregate_kernel<<<aggBlocks, 256, 0, stream>>>((const float2*)bufA, rowptr, csr,
                                                    dinv, b1, (float2*)bufB, 1);

    // ---- layer 2: hp2 = (h1@W2)*dinv -> bufA ; aggregate+bias -> out ----
    gemm_xw<<<gemmBlocks, 256, 0, stream>>>(bufB, W2, dinv, bufA, N_NODES);
    aggregate_kernel<<<aggBlocks, 256, 0, stream>>>((const float2*)bufA, rowptr, csr,
                                                    dinv, b2, (float2*)out, 0);
}

// Round 3
// 341.770 us; speedup vs baseline: 8.5826x; 1.1790x over previous
//
#include <hip/hip_runtime.h>

#define N_NODES 50000
#define N_EDGES 800000
#define DIM 128

// ---------------- degree histogram (int) ----------------

__global__ __launch_bounds__(256) void deg_kernel(const int* __restrict__ dst,
                                                  int* __restrict__ degi, int nE) {
    int e = blockIdx.x * 256 + threadIdx.x;
    if (e < nE) atomicAdd(&degi[dst[e]], 1);
}

// ---------------- parallel scan, stage 1: per-1024-chunk inclusive scan ----

__global__ __launch_bounds__(1024) void scan_local(const int* __restrict__ cnt,
                                                   int* __restrict__ rowptr,   // local incl -> rowptr[i+1]
                                                   int* __restrict__ bsum, int n) {
    __shared__ int wsum[16];
    const int t = threadIdx.x;
    const int lane = t & 63;
    const int wid = t >> 6;
    int i = blockIdx.x * 1024 + t;
    int v = (i < n) ? cnt[i] : 0;
    int incl = v;
#pragma unroll
    for (int off = 1; off < 64; off <<= 1) {
        int u = __shfl_up(incl, off, 64);
        if (lane >= off) incl += u;
    }
    if (lane == 63) wsum[wid] = incl;
    __syncthreads();
    if (wid == 0) {
        int wv = (lane < 16) ? wsum[lane] : 0;
#pragma unroll
        for (int off = 1; off < 16; off <<= 1) {
            int u = __shfl_up(wv, off, 64);
            if (lane >= off) wv += u;
        }
        if (lane < 16) wsum[lane] = wv;
    }
    __syncthreads();
    int tot = incl + ((wid > 0) ? wsum[wid - 1] : 0);
    if (i < n) rowptr[i + 1] = tot;            // local inclusive, offset added in stage 3
    if (t == 1023) bsum[blockIdx.x] = tot;     // chunk total (padding contributes 0)
}

// ---------------- stage 2: 1-wave exclusive scan of block sums (nb<=64) ----

__global__ __launch_bounds__(64) void scan_bsums(int* __restrict__ bsum, int nb) {
    int lane = threadIdx.x;
    int v = (lane < nb) ? bsum[lane] : 0;
    int incl = v;
#pragma unroll
    for (int off = 1; off < 64; off <<= 1) {
        int u = __shfl_up(incl, off, 64);
        if (lane >= off) incl += u;
    }
    if (lane < nb) bsum[lane] = incl - v;      // exclusive offset
}

// ---------------- stage 3: apply offsets, build cursor, dinv ----------------

__global__ __launch_bounds__(256) void scan_apply(const int* __restrict__ cnt,
                                                  int* __restrict__ rowptr,
                                                  int* __restrict__ cursor,
                                                  const int* __restrict__ bsum,
                                                  float* __restrict__ dinv, int n) {
    int i = blockIdx.x * 256 + threadIdx.x;
    if (i == 0) rowptr[0] = 0;
    if (i < n) {
        int incl = rowptr[i + 1] + bsum[i >> 10];
        rowptr[i + 1] = incl;
        cursor[i] = incl - cnt[i];
        dinv[i] = rsqrtf((float)cnt[i] + 1.0f);   // +1 self-loop
    }
}

// ---------------- CSR fill (grouped by dst, entries = src) ----------------

__global__ __launch_bounds__(256) void fill_kernel(const int* __restrict__ src,
                                                   const int* __restrict__ dst,
                                                   int* __restrict__ cursor,
                                                   int* __restrict__ csr, int nE) {
    int e = blockIdx.x * 256 + threadIdx.x;
    if (e >= nE) return;
    int d = dst[e];
    int pos = atomicAdd(&cursor[d], 1);
    csr[pos] = src[e];
}

// ---------------- GEMM: O[n,128] = (X[n,128] @ W[128,128]) * dinv[row] -----
// 64 rows/block; thread = 8 rows x 4 cols (32 FMA per k). X staged in LDS
// (broadcast reads, 2 distinct addrs/wave = free), W float4 through L1.

__global__ __launch_bounds__(256) void gemm_xw(const float* __restrict__ X,
                                               const float* __restrict__ W,
                                               const float* __restrict__ dinv,
                                               float* __restrict__ O, int nrows) {
    __shared__ float Xs[64][128];
    const int rbase = blockIdx.x * 64;
    const int t = threadIdx.x;

    // stage 64x128 floats = 2048 float4, 8 per thread, coalesced
    for (int idx = t; idx < 2048; idx += 256) {
        int r = idx >> 5;
        int gr = rbase + r;
        float4 v = make_float4(0.f, 0.f, 0.f, 0.f);
        if (gr < nrows) v = ((const float4*)X)[(size_t)gr * 32 + (idx & 31)];
        ((float4*)Xs)[idx] = v;
    }
    __syncthreads();

    const int ct = t & 31;        // cols [ct*4, ct*4+4)
    const int rt = t >> 5;        // rows [rt*8, rt*8+8)
    float4 acc[8];
#pragma unroll
    for (int j = 0; j < 8; ++j) acc[j] = make_float4(0.f, 0.f, 0.f, 0.f);

    const float4* W4 = (const float4*)W;
#pragma unroll 4
    for (int k = 0; k < 128; ++k) {
        float4 w = W4[k * 32 + ct];
#pragma unroll
        for (int j = 0; j < 8; ++j) {
            float xv = Xs[rt * 8 + j][k];
            acc[j].x += xv * w.x;
            acc[j].y += xv * w.y;
            acc[j].z += xv * w.z;
            acc[j].w += xv * w.w;
        }
    }

#pragma unroll
    for (int j = 0; j < 8; ++j) {
        int r = rbase + rt * 8 + j;
        if (r < nrows) {
            float di = dinv[r];
            float4 o = make_float4(acc[j].x * di, acc[j].y * di,
                                   acc[j].z * di, acc[j].w * di);
            ((float4*)O)[(size_t)r * 32 + ct] = o;
        }
    }
}

// ---------------- CSR aggregate: out[d] = dinv[d]*(sum hp[s] + hp[d]) + b --
// one wave per node, float2 per lane; unroll 8 to keep gathers in flight

__global__ __launch_bounds__(256) void aggregate_kernel(const float2* __restrict__ H2,
                                                        const int* __restrict__ rowptr,
                                                        const int* __restrict__ csr,
                                                        const float* __restrict__ dinv,
                                                        const float* __restrict__ b,
                                                        float2* __restrict__ out,
                                                        int relu) {
    int node = blockIdx.x * 4 + (threadIdx.x >> 6);
    if (node >= N_NODES) return;
    int lane = threadIdx.x & 63;

    float2 acc = H2[(size_t)node * 64 + lane];       // self-loop term hp[d]
    int beg = rowptr[node], end = rowptr[node + 1];
    int j = beg;
    for (; j + 8 <= end; j += 8) {
        int s0 = csr[j],     s1 = csr[j + 1], s2 = csr[j + 2], s3 = csr[j + 3];
        int s4 = csr[j + 4], s5 = csr[j + 5], s6 = csr[j + 6], s7 = csr[j + 7];
        float2 v0 = H2[(size_t)s0 * 64 + lane];
        float2 v1 = H2[(size_t)s1 * 64 + lane];
        float2 v2 = H2[(size_t)s2 * 64 + lane];
        float2 v3 = H2[(size_t)s3 * 64 + lane];
        float2 v4 = H2[(size_t)s4 * 64 + lane];
        float2 v5 = H2[(size_t)s5 * 64 + lane];
        float2 v6 = H2[(size_t)s6 * 64 + lane];
        float2 v7 = H2[(size_t)s7 * 64 + lane];
        acc.x += ((v0.x + v1.x) + (v2.x + v3.x)) + ((v4.x + v5.x) + (v6.x + v7.x));
        acc.y += ((v0.y + v1.y) + (v2.y + v3.y)) + ((v4.y + v5.y) + (v6.y + v7.y));
    }
    for (; j + 2 <= end; j += 2) {
        int s0 = csr[j], s1 = csr[j + 1];
        float2 v0 = H2[(size_t)s0 * 64 + lane];
        float2 v1 = H2[(size_t)s1 * 64 + lane];
        acc.x += v0.x + v1.x;
        acc.y += v0.y + v1.y;
    }
    for (; j < end; ++j) {
        int s = csr[j];
        float2 v = H2[(size_t)s * 64 + lane];
        acc.x += v.x; acc.y += v.y;
    }

    float di = dinv[node];
    int c = lane * 2;
    float o0 = acc.x * di + b[c];
    float o1 = acc.y * di + b[c + 1];
    if (relu) { o0 = fmaxf(o0, 0.0f); o1 = fmaxf(o1, 0.0f); }
    out[(size_t)node * 64 + lane] = make_float2(o0, o1);
}

// ---------------- launch ----------------

extern "C" void kernel_launch(void* const* d_in, const int* in_sizes, int n_in,
                              void* d_out, int out_size, void* d_ws, size_t ws_size,
                              hipStream_t stream) {
    const float* x  = (const float*)d_in[0];
    const int*   ei = (const int*)d_in[1];
    const float* W1 = (const float*)d_in[2];
    const float* b1 = (const float*)d_in[3];
    const float* W2 = (const float*)d_in[4];
    const float* b2 = (const float*)d_in[5];
    float* out = (float*)d_out;

    const int* src = ei;             // edge_index[0]
    const int* dst = ei + N_EDGES;   // edge_index[1]

    // workspace layout (all 1KB-aligned)
    char* p = (char*)d_ws;
    int*   degi   = (int*)p;                 p += ((N_NODES * 4 + 1023) & ~1023);
    float* dinv   = (float*)p;               p += ((N_NODES * 4 + 1023) & ~1023);
    int*   rowptr = (int*)p;                 p += (((N_NODES + 1) * 4 + 1023) & ~1023);
    int*   cursor = (int*)p;                 p += ((N_NODES * 4 + 1023) & ~1023);
    int*   bsum   = (int*)p;                 p += 1024;
    int*   csr    = (int*)p;                 p += ((N_EDGES * 4 + 1023) & ~1023);
    float* bufA   = (float*)p;               p += (size_t)N_NODES * DIM * sizeof(float);
    float* bufB   = (float*)p;

    const int scanBlocks = (N_NODES + 1023) / 1024;   // 49
    const int gemmBlocks = (N_NODES + 63) / 64;       // 782
    const int aggBlocks  = (N_NODES + 3) / 4;         // 12500
    const int nodeBlocks = (N_NODES + 255) / 256;
    const int edgeBlocks = (N_EDGES + 255) / 256;

    // ---- build CSR (grouped by dst) + dinv ----
    hipMemsetAsync(degi, 0, N_NODES * sizeof(int), stream);
    deg_kernel<<<edgeBlocks, 256, 0, stream>>>(dst, degi, N_EDGES);
    scan_local<<<scanBlocks, 1024, 0, stream>>>(degi, rowptr, bsum, N_NODES);
    scan_bsums<<<1, 64, 0, stream>>>(bsum, scanBlocks);
    scan_apply<<<nodeBlocks, 256, 0, stream>>>(degi, rowptr, cursor, bsum, dinv, N_NODES);
    fill_kernel<<<edgeBlocks, 256, 0, stream>>>(src, dst, cursor, csr, N_EDGES);

    // ---- layer 1: hp1 = (x@W1)*dinv -> bufA ; aggregate+bias+relu -> bufB ----
    gemm_xw<<<gemmBlocks, 256, 0, stream>>>(x, W1, dinv, bufA, N_NODES);
    aggregate_kernel<<<aggBlocks, 256, 0, stream>>>((const float2*)bufA, rowptr, csr,
                                                    dinv, b1, (float2*)bufB, 1);

    // ---- layer 2: hp2 = (h1@W2)*dinv -> bufA ; aggregate+bias -> out ----
    gemm_xw<<<gemmBlocks, 256, 0, stream>>>(bufB, W2, dinv, bufA, N_NODES);
    aggregate_kernel<<<aggBlocks, 256, 0, stream>>>((const float2*)bufA, rowptr, csr,
                                                    dinv, b2, (float2*)out, 0);
}